// Round 6
// baseline (291.604 us; speedup 1.0000x reference)
//
#include <hip/hip_runtime.h>
#include <stdint.h>

typedef unsigned short u16;
typedef unsigned int   u32;
typedef __attribute__((ext_vector_type(8))) short short8;
typedef __attribute__((ext_vector_type(4))) float f32x4;

static constexpr int kN = 16384;
static constexpr float kEPS = 1e-5f;

__device__ __forceinline__ u16 f2bf(float x) {
  u32 u = __float_as_uint(x);
  u32 r = (u + 0x7fffu + ((u >> 16) & 1u)) >> 16;
  return (u16)r;
}
__device__ __forceinline__ float bf2f(u16 x) {
  return __uint_as_float(((u32)x) << 16);
}
__device__ __forceinline__ void ldbf8(const u16* p, float* o) {
  uint4 v = *(const uint4*)p;
  o[0] = __uint_as_float(v.x << 16);  o[1] = __uint_as_float(v.x & 0xffff0000u);
  o[2] = __uint_as_float(v.y << 16);  o[3] = __uint_as_float(v.y & 0xffff0000u);
  o[4] = __uint_as_float(v.z << 16);  o[5] = __uint_as_float(v.z & 0xffff0000u);
  o[6] = __uint_as_float(v.w << 16);  o[7] = __uint_as_float(v.w & 0xffff0000u);
}
__device__ __forceinline__ void gll16(const u16* g, u16* l) {
  __builtin_amdgcn_global_load_lds(
      (const __attribute__((address_space(1))) void*)g,
      (__attribute__((address_space(3))) void*)l, 16, 0, 0);
}

// ================= fused setup: zero | weight cast+transpose | pbc | W2f | prep =================
struct WSet {
  const float* s[8]; u16* d[8];
  int K[8]; int N[8]; int dstride[8]; int coff[8];
};

__global__ __launch_bounds__(256) void k_setup(WSet ws,
                                               u32* __restrict__ zero_area,
                                               const float* __restrict__ proj_b,
                                               const float* __restrict__ pe_b2,
                                               float* __restrict__ pbc,
                                               const float* __restrict__ uw1,
                                               const float* __restrict__ ub1,
                                               const float* __restrict__ uw2,
                                               const float* __restrict__ ub2,
                                               u16* __restrict__ W2f,
                                               float* __restrict__ bbf,
                                               const int* __restrict__ coords,
                                               const float* __restrict__ feats,
                                               const float* __restrict__ pw1,
                                               const float* __restrict__ pb1,
                                               u16* __restrict__ A1,
                                               u16* __restrict__ A2) {
  int w = blockIdx.y;
  if (w == 8) {  // zero: cnt, cursor, pS, pQ, bar, arrive
    int idx = blockIdx.x * 256 + threadIdx.x;
    if (idx < 32960) zero_area[idx] = 0u;
    return;
  }
  if (w == 9) {  // pbc + fused tail weight
    int bx = blockIdx.x;
    if (bx == 0) {
      pbc[threadIdx.x] = proj_b[threadIdx.x] + pe_b2[threadIdx.x];
    } else if (bx < 65) {
      int n = bx - 1;          // 0..63
      int k = threadIdx.x;     // 0..255
      float s = 0.f;
      for (int j = 0; j < 64; j++) s += uw1[k * 64 + j] * uw2[(64 + j) * 64 + n];
      W2f[n * 320 + k] = f2bf(s);
      if (k < 64) W2f[n * 320 + 256 + k] = f2bf(uw2[k * 64 + n]);
      if (k == 0) {
        float b = ub2[n];
        for (int j = 0; j < 64; j++) b += ub1[j] * uw2[(64 + j) * 64 + n];
        bbf[n] = b;
      }
    }
    return;
  }
  if (w == 10) {  // prep: A1 = [feats | relu(PE hidden)] (Nx192); A2[:,256:320] = feats bf16
    int r0 = blockIdx.x * 32;
#pragma unroll
    for (int s = 0; s < 3; s++) {
      int j = threadIdx.x + s * 256;  // 0..767 = 32 rows x 24 segs
      int row = j / 24, seg = j % 24;
      int n = r0 + row;
      u16 o[8];
      if (seg < 8) {
        const float* fp = feats + (size_t)n * 64 + seg * 8;
        float4 a = *(const float4*)fp;
        float4 b = *(const float4*)(fp + 4);
        o[0] = f2bf(a.x); o[1] = f2bf(a.y); o[2] = f2bf(a.z); o[3] = f2bf(a.w);
        o[4] = f2bf(b.x); o[5] = f2bf(b.y); o[6] = f2bf(b.z); o[7] = f2bf(b.w);
        *(uint4*)(A2 + (size_t)n * 320 + 256 + seg * 8) = *(uint4*)o;
      } else {
        int jj0 = (seg - 8) * 8;
        float x0 = (float)coords[n * 3 + 0] * (1.f / 127.f);
        float x1 = (float)coords[n * 3 + 1] * (1.f / 127.f);
        float x2 = (float)coords[n * 3 + 2] * (1.f / 127.f);
#pragma unroll
        for (int u = 0; u < 8; u++) {
          int jj = jj0 + u;
          float hv = pb1[jj] + x0 * pw1[jj] + x1 * pw1[128 + jj] + x2 * pw1[256 + jj];
          o[u] = f2bf(fmaxf(hv, 0.f));
        }
        *(uint4*)(A1 + (size_t)n * 192 + seg * 8) = *(uint4*)o;
        continue;
      }
      *(uint4*)(A1 + (size_t)n * 192 + seg * 8) = *(uint4*)o;
    }
    return;
  }
  // weight cast+transpose: S (K x N fp32) -> D[n*dstride+coff+k] bf16
  const float* S = ws.s[w]; u16* D = ws.d[w];
  int K = ws.K[w], N = ws.N[w], ds = ws.dstride[w], co = ws.coff[w];
  int ntx = N >> 5, tiles = ntx * (K >> 5);
  int t = blockIdx.x;
  if (t >= tiles) return;
  int n0 = (t % ntx) * 32, k0 = (t / ntx) * 32;
  __shared__ float st[32][33];
  int tr = threadIdx.x >> 3, tc4 = (threadIdx.x & 7) * 4;
  float4 v = *(const float4*)(S + (size_t)(k0 + tr) * N + n0 + tc4);
  st[tc4 + 0][tr] = v.x; st[tc4 + 1][tr] = v.y;
  st[tc4 + 2][tr] = v.z; st[tc4 + 3][tr] = v.w;
  __syncthreads();
  u16 o4[4];
  o4[0] = f2bf(st[tr][tc4 + 0]); o4[1] = f2bf(st[tr][tc4 + 1]);
  o4[2] = f2bf(st[tr][tc4 + 2]); o4[3] = f2bf(st[tr][tc4 + 3]);
  *(uint2*)(D + (size_t)(n0 + tr) * ds + co + k0 + tc4) = *(uint2*)o4;
}

// ================= fused neighbor pipeline: hist | scan | scatter | select =================
// 64 blocks (co-resident on 256 CUs) with software grid barriers.
__device__ __forceinline__ void gbar(u32* bar, u32 target) {
  __syncthreads();
  if (threadIdx.x == 0) {
    __threadfence();
    __hip_atomic_fetch_add(bar, 1u, __ATOMIC_RELEASE, __HIP_MEMORY_SCOPE_AGENT);
    while (__hip_atomic_load(bar, __ATOMIC_ACQUIRE, __HIP_MEMORY_SCOPE_AGENT) < target) {}
    __threadfence();
  }
  __syncthreads();
}

__global__ __launch_bounds__(256) void k_grid(const int* __restrict__ coords,
                                              u32* __restrict__ cnt,
                                              u32* __restrict__ cursor,
                                              u32* __restrict__ startb,
                                              u32* __restrict__ pts,
                                              int* __restrict__ idxo,
                                              u32* __restrict__ bar) {
  int n = blockIdx.x * 256 + threadIdx.x;
  int x = coords[n * 3], y = coords[n * 3 + 1], z = coords[n * 3 + 2];
  int c = x * 128 + y;
  atomicAdd(&cnt[c], 1u);
  gbar(bar, 64);
  if (blockIdx.x == 0) {  // scan (single block)
    __shared__ u32 tots[256];
    int t = threadIdx.x;
    int base = t * 64;
    u32 s = 0;
    for (int i = 0; i < 64; i++) s += cnt[base + i];
    tots[t] = s;
    __syncthreads();
    if (t == 0) {
      u32 run = 0;
      for (int i = 0; i < 256; i++) { u32 v = tots[i]; tots[i] = run; run += v; }
    }
    __syncthreads();
    u32 run = tots[t];
    for (int i = 0; i < 64; i++) { startb[base + i] = run; run += cnt[base + i]; }
  }
  gbar(bar, 128);
  {  // scatter
    u32 slot = atomicAdd(&cursor[c], 1u);
    pts[startb[c] + slot] = ((u32)z << 14) | (u32)n;
  }
  gbar(bar, 192);
  {  // select: top-16 by (dist, idx) ascending — matches jax.lax.top_k ties
    u32 best[16];
#pragma unroll
    for (int j = 0; j < 16; j++) best[j] = 0xFFFFFFFFu;
    const int dxs[13] = {0, -1, 1, 0, 0, -2, 2, 0, 0, -1, -1, 1, 1};
    const int dys[13] = {0, 0, 0, -1, 1, 0, 0, -2, 2, -1, 1, -1, 1};
    const int dbs[13] = {0, 1, 1, 1, 1, 2, 2, 2, 2, 2, 2, 2, 2};
#pragma unroll
    for (int t = 0; t < 13; t++) {
      int xx = x + dxs[t], yy = y + dys[t];
      if (xx < 0 || xx > 127 || yy < 0 || yy > 127) continue;
      int cc = xx * 128 + yy;
      u32 s0 = startb[cc], e0 = s0 + cnt[cc];
      for (u32 i = s0; i < e0; ++i) {
        u32 p = pts[i];
        int zq = (int)(p >> 14);
        int id = (int)(p & 16383u);
        int az = z - zq; az = az < 0 ? -az : az;
        int dd = dbs[t] + az;
        u32 key = (dd <= 2) ? (((u32)dd << 14) | (u32)id) : 0xFFFFFFFFu;
#pragma unroll
        for (int j = 0; j < 16; j++) {
          u32 lo = min(best[j], key);
          u32 hi = max(best[j], key);
          best[j] = lo; key = hi;
        }
      }
    }
#pragma unroll
    for (int j = 0; j < 16; j++)
      idxo[n * 16 + j] = (best[j] == 0xFFFFFFFFu) ? -1 : (int)(best[j] & 16383u);
  }
}

// ================= row-persistent src+QKV: 64 rows/block =================
// src = A1(64x192) @ W1T^T + pbc  (kept in LDS), QKV = src @ qkvT^T -> global
__global__ __launch_bounds__(256) void k_src_qkv(const u16* __restrict__ A1,
                                                 const u16* __restrict__ W1T,
                                                 const float* __restrict__ pbc,
                                                 const u16* __restrict__ qkvT,
                                                 u16* __restrict__ QKV) {
  __shared__ __align__(16) u16 reg1[16896];  // a1 tile (64x200) then B tile (64x264)
  __shared__ __align__(16) u16 srcL[16896];  // src tile 64x264 (pad 8)
  __shared__ __align__(16) u16 Bs[2048];     // 64x32 K-iter staging
  const int tid = threadIdx.x;
  const int wave = tid >> 6, lane = tid & 63;
  const int bm = blockIdx.x * 64;
  const int wr = (wave >> 1) * 32, wc = (wave & 1) * 32;
  const int fr = lane & 15, fk = (lane >> 4) * 8, rq = (lane >> 4) * 4;

  // stage A1 tile padded (stride 200)
#pragma unroll
  for (int s = 0; s < 6; s++) {
    int c = tid + s * 256;  // 0..1535
    int row = c / 24, kc = c % 24;
    *(uint4*)&reg1[row * 200 + kc * 8] =
        *(const uint4*)(A1 + (size_t)(bm + row) * 192 + kc * 8);
  }
  __syncthreads();

  // src phase
  for (int nc = 0; nc < 4; nc++) {
    f32x4 acc[2][2];
#pragma unroll
    for (int i = 0; i < 2; i++)
#pragma unroll
      for (int j = 0; j < 2; j++)
#pragma unroll
        for (int r = 0; r < 4; r++) acc[i][j][r] = 0.f;
    for (int k0 = 0; k0 < 192; k0 += 32) {
      {
        int g = wave * 64 + lane;  // 0..255
        int row = g >> 2, ko = (g & 3) * 8;
        gll16(W1T + (size_t)(nc * 64 + row) * 192 + k0 + ko, Bs + g * 8);
      }
      __syncthreads();
      short8 af[2], bg[2];
#pragma unroll
      for (int i = 0; i < 2; i++)
        af[i] = *(const short8*)&reg1[(wr + i * 16 + fr) * 200 + k0 + fk];
#pragma unroll
      for (int j = 0; j < 2; j++)
        bg[j] = *(const short8*)&Bs[(wc + j * 16 + fr) * 32 + fk];
#pragma unroll
      for (int i = 0; i < 2; i++)
#pragma unroll
        for (int j = 0; j < 2; j++)
          acc[i][j] = __builtin_amdgcn_mfma_f32_16x16x32_bf16(af[i], bg[j], acc[i][j], 0, 0, 0);
      __syncthreads();
    }
#pragma unroll
    for (int j = 0; j < 2; j++) {
      int col = nc * 64 + wc + j * 16 + fr;
      float bv = pbc[col];
#pragma unroll
      for (int i = 0; i < 2; i++) {
        int rb = wr + i * 16 + rq;
#pragma unroll
        for (int r = 0; r < 4; r++)
          srcL[(rb + r) * 264 + col] = f2bf(acc[i][j][r] + bv);
      }
    }
  }
  __syncthreads();

  // QKV phase: stream qkvT 64-row chunks into reg1 (padded 264)
  for (int qc = 0; qc < 12; qc++) {
#pragma unroll
    for (int s = 0; s < 8; s++) {
      int c = tid + s * 256;  // 0..2047
      int row = c >> 5, kc = c & 31;
      *(uint4*)&reg1[row * 264 + kc * 8] =
          *(const uint4*)(qkvT + (size_t)(qc * 64 + row) * 256 + kc * 8);
    }
    __syncthreads();
    f32x4 acc[2][2];
#pragma unroll
    for (int i = 0; i < 2; i++)
#pragma unroll
      for (int j = 0; j < 2; j++)
#pragma unroll
        for (int r = 0; r < 4; r++) acc[i][j][r] = 0.f;
#pragma unroll
    for (int k0 = 0; k0 < 256; k0 += 32) {
      short8 af[2], bg[2];
#pragma unroll
      for (int i = 0; i < 2; i++)
        af[i] = *(const short8*)&srcL[(wr + i * 16 + fr) * 264 + k0 + fk];
#pragma unroll
      for (int j = 0; j < 2; j++)
        bg[j] = *(const short8*)&reg1[(wc + j * 16 + fr) * 264 + k0 + fk];
#pragma unroll
      for (int i = 0; i < 2; i++)
#pragma unroll
        for (int j = 0; j < 2; j++)
          acc[i][j] = __builtin_amdgcn_mfma_f32_16x16x32_bf16(af[i], bg[j], acc[i][j], 0, 0, 0);
    }
#pragma unroll
    for (int j = 0; j < 2; j++) {
      int col = qc * 64 + wc + j * 16 + fr;
#pragma unroll
      for (int i = 0; i < 2; i++) {
        int rb = wr + i * 16 + rq;
#pragma unroll
        for (int r = 0; r < 4; r++)
          QKV[(size_t)(bm + rb + r) * 768 + col] = f2bf(acc[i][j][r]);
      }
    }
    __syncthreads();
  }
}

// ================= attention: one thread per (query, head), cell-sorted order =================
__global__ __launch_bounds__(256) void k_attn(const u16* __restrict__ QKV,
                                              const u32* __restrict__ pts,
                                              const int* __restrict__ idx,
                                              const float* __restrict__ bq,
                                              const float* __restrict__ bk,
                                              const float* __restrict__ bv,
                                              u16* __restrict__ outp) {
  int gid = blockIdx.x * 256 + threadIdx.x;
  int n = (int)(pts[gid >> 3] & 16383u), h = gid & 7;
  const int* ip = idx + n * 16;
  const int hb = h * 32;
  float q[32];
  {
    int i0 = ip[0];  // slot0: dist 0 (self) — always valid
    const u16* qp = QKV + (size_t)i0 * 768 + hb;
#pragma unroll
    for (int j = 0; j < 32; j += 8) ldbf8(qp + j, &q[j]);
#pragma unroll
    for (int j = 0; j < 32; j++) q[j] += bq[hb + j];
  }
  float qbk = 0.f;
#pragma unroll
  for (int j = 0; j < 32; j++) qbk += q[j] * bk[hb + j];
  float s[16]; int ii[16];
#pragma unroll
  for (int m = 0; m < 16; m++) {
    int i = ip[m]; ii[m] = i;
    float d = qbk;
    if (i >= 0) {
      const u16* kp = QKV + (size_t)i * 768 + 256 + hb;
      float kv[32];
#pragma unroll
      for (int j = 0; j < 32; j += 8) ldbf8(kp + j, &kv[j]);
#pragma unroll
      for (int j = 0; j < 32; j++) d += q[j] * kv[j];
    }
    s[m] = d * 0.17677669529663689f;  // 1/sqrt(32)
  }
  float mx = s[0];
#pragma unroll
  for (int m = 1; m < 16; m++) mx = fmaxf(mx, s[m]);
  float sum = 0.f;
#pragma unroll
  for (int m = 0; m < 16; m++) { s[m] = __expf(s[m] - mx); sum += s[m]; }
  float inv = 1.f / sum;
  float o[32];
#pragma unroll
  for (int j = 0; j < 32; j++) o[j] = 0.f;
#pragma unroll
  for (int m = 0; m < 16; m++) {
    if (ii[m] >= 0) {
      const u16* vp = QKV + (size_t)ii[m] * 768 + 512 + hb;
      float vv[32];
#pragma unroll
      for (int j = 0; j < 32; j += 8) ldbf8(vp + j, &vv[j]);
#pragma unroll
      for (int j = 0; j < 32; j++) o[j] += s[m] * vv[j];
    }
  }
  u16* op = outp + (size_t)n * 256 + hb;
#pragma unroll
  for (int j = 0; j < 32; j += 8) {
    u16 tmp[8];
#pragma unroll
    for (int jj = 0; jj < 8; jj++) tmp[jj] = f2bf(o[j + jj] * inv + bv[hb + j + jj]);
    *(uint4*)(op + j) = *(uint4*)tmp;
  }
}

// ================= row-persistent wo + FFN + residual + LN: 64 rows/block =================
__global__ __launch_bounds__(256) void k_ffn_ln(const u16* __restrict__ aoIn,
                                                const u16* __restrict__ woT,
                                                const float* __restrict__ bo,
                                                const u16* __restrict__ fw1T,
                                                const float* __restrict__ fb1,
                                                const u16* __restrict__ fw2T,
                                                const float* __restrict__ fb2,
                                                const float* __restrict__ lng,
                                                const float* __restrict__ lnb,
                                                u16* __restrict__ A2) {
  __shared__ __align__(16) u16 aoL[16896];  // ao 64x264
  __shared__ __align__(16) u16 h1L[16896];  // h1 half 64x264
  __shared__ __align__(16) u16 As[2048];
  __shared__ __align__(16) u16 Bs[2048];
  const int tid = threadIdx.x;
  const int wave = tid >> 6, lane = tid & 63;
  const int bm = blockIdx.x * 64;
  const int wr = (wave >> 1) * 32, wc = (wave & 1) * 32;
  const int fr = lane & 15, fk = (lane >> 4) * 8, rq = (lane >> 4) * 4;
  const int g = wave * 64 + lane;
  const int grow = g >> 2, gko = (g & 3) * 8;

  // phase 1: ao = aoIn @ woT + bo  -> aoL
  for (int nc = 0; nc < 4; nc++) {
    f32x4 acc[2][2];
#pragma unroll
    for (int i = 0; i < 2; i++)
#pragma unroll
      for (int j = 0; j < 2; j++)
#pragma unroll
        for (int r = 0; r < 4; r++) acc[i][j][r] = 0.f;
    for (int k0 = 0; k0 < 256; k0 += 32) {
      gll16(aoIn + (size_t)(bm + grow) * 256 + k0 + gko, As + g * 8);
      gll16(woT + (size_t)(nc * 64 + grow) * 256 + k0 + gko, Bs + g * 8);
      __syncthreads();
      short8 af[2], bg[2];
#pragma unroll
      for (int i = 0; i < 2; i++)
        af[i] = *(const short8*)&As[(wr + i * 16 + fr) * 32 + fk];
#pragma unroll
      for (int j = 0; j < 2; j++)
        bg[j] = *(const short8*)&Bs[(wc + j * 16 + fr) * 32 + fk];
#pragma unroll
      for (int i = 0; i < 2; i++)
#pragma unroll
        for (int j = 0; j < 2; j++)
          acc[i][j] = __builtin_amdgcn_mfma_f32_16x16x32_bf16(af[i], bg[j], acc[i][j], 0, 0, 0);
      __syncthreads();
    }
#pragma unroll
    for (int j = 0; j < 2; j++) {
      int col = nc * 64 + wc + j * 16 + fr;
      float bv = bo[col];
#pragma unroll
      for (int i = 0; i < 2; i++) {
        int rb = wr + i * 16 + rq;
#pragma unroll
        for (int r = 0; r < 4; r++)
          aoL[(rb + r) * 264 + col] = f2bf(acc[i][j][r] + bv);
      }
    }
  }
  __syncthreads();

  // phase 2: x = ao + relu(ao@fw1+b1)@fw2 (accumulated over two K-halves)
  f32x4 xacc[4][2][2];
#pragma unroll
  for (int xc = 0; xc < 4; xc++)
#pragma unroll
    for (int i = 0; i < 2; i++)
#pragma unroll
      for (int j = 0; j < 2; j++)
#pragma unroll
        for (int r = 0; r < 4; r++) xacc[xc][i][j][r] = 0.f;

  for (int h = 0; h < 2; h++) {
    // h1 half = relu(ao @ fw1[half] + b1)
    for (int nc = 0; nc < 4; nc++) {
      f32x4 acc[2][2];
#pragma unroll
      for (int i = 0; i < 2; i++)
#pragma unroll
        for (int j = 0; j < 2; j++)
#pragma unroll
          for (int r = 0; r < 4; r++) acc[i][j][r] = 0.f;
      for (int k0 = 0; k0 < 256; k0 += 32) {
        gll16(fw1T + (size_t)(h * 256 + nc * 64 + grow) * 256 + k0 + gko, Bs + g * 8);
        __syncthreads();
        short8 af[2], bg[2];
#pragma unroll
        for (int i = 0; i < 2; i++)
          af[i] = *(const short8*)&aoL[(wr + i * 16 + fr) * 264 + k0 + fk];
#pragma unroll
        for (int j = 0; j < 2; j++)
          bg[j] = *(const short8*)&Bs[(wc + j * 16 + fr) * 32 + fk];
#pragma unroll
        for (int i = 0; i < 2; i++)
#pragma unroll
          for (int j = 0; j < 2; j++)
            acc[i][j] = __builtin_amdgcn_mfma_f32_16x16x32_bf16(af[i], bg[j], acc[i][j], 0, 0, 0);
        __syncthreads();
      }
#pragma unroll
      for (int j = 0; j < 2; j++) {
        int col = nc * 64 + wc + j * 16 + fr;
        float bv = fb1[h * 256 + col];
#pragma unroll
        for (int i = 0; i < 2; i++) {
          int rb = wr + i * 16 + rq;
#pragma unroll
          for (int r = 0; r < 4; r++)
            h1L[(rb + r) * 264 + col] = f2bf(fmaxf(acc[i][j][r] + bv, 0.f));
        }
      }
    }
    __syncthreads();
    // x += h1half @ fw2[rows, half-k]
    for (int xc = 0; xc < 4; xc++) {
      for (int k0 = 0; k0 < 256; k0 += 32) {
        gll16(fw2T + (size_t)(xc * 64 + grow) * 512 + h * 256 + k0 + gko, Bs + g * 8);
        __syncthreads();
        short8 af[2], bg[2];
#pragma unroll
        for (int i = 0; i < 2; i++)
          af[i] = *(const short8*)&h1L[(wr + i * 16 + fr) * 264 + k0 + fk];
#pragma unroll
        for (int j = 0; j < 2; j++)
          bg[j] = *(const short8*)&Bs[(wc + j * 16 + fr) * 32 + fk];
#pragma unroll
        for (int i = 0; i < 2; i++)
#pragma unroll
          for (int j = 0; j < 2; j++)
            xacc[xc][i][j] = __builtin_amdgcn_mfma_f32_16x16x32_bf16(af[i], bg[j], xacc[xc][i][j], 0, 0, 0);
        __syncthreads();
      }
    }
  }

  // epilogue: residual + LN -> A2[:,0:256]
  float rowS[2][4], rowQ[2][4];
#pragma unroll
  for (int i = 0; i < 2; i++)
#pragma unroll
    for (int r = 0; r < 4; r++) { rowS[i][r] = 0.f; rowQ[i][r] = 0.f; }
#pragma unroll
  for (int xc = 0; xc < 4; xc++)
#pragma unroll
    for (int j = 0; j < 2; j++) {
      int col = xc * 64 + wc + j * 16 + fr;
      float f2 = fb2[col];
#pragma unroll
      for (int i = 0; i < 2; i++) {
        int rb = wr + i * 16 + rq;
#pragma unroll
        for (int r = 0; r < 4; r++) {
          float v = xacc[xc][i][j][r] + f2 + bf2f(aoL[(rb + r) * 264 + col]);
          xacc[xc][i][j][r] = v;
          rowS[i][r] += v; rowQ[i][r] += v * v;
        }
      }
    }
#pragma unroll
  for (int off = 1; off < 16; off <<= 1) {
#pragma unroll
    for (int i = 0; i < 2; i++)
#pragma unroll
      for (int r = 0; r < 4; r++) {
        rowS[i][r] += __shfl_xor(rowS[i][r], off);
        rowQ[i][r] += __shfl_xor(rowQ[i][r], off);
      }
  }
  float* redS = (float*)As;        // 128 floats
  float* redQ = redS + 128;        // fits in As(4KB)
  if (fr == 0) {
#pragma unroll
    for (int i = 0; i < 2; i++)
#pragma unroll
      for (int r = 0; r < 4; r++) {
        int row = wr + i * 16 + rq + r;
        redS[row * 2 + (wave & 1)] = rowS[i][r];
        redQ[row * 2 + (wave & 1)] = rowQ[i][r];
      }
  }
  __syncthreads();
  float mu[2][4], rs[2][4];
#pragma unroll
  for (int i = 0; i < 2; i++)
#pragma unroll
    for (int r = 0; r < 4; r++) {
      int row = wr + i * 16 + rq + r;
      float S = redS[row * 2] + redS[row * 2 + 1];
      float Q = redQ[row * 2] + redQ[row * 2 + 1];
      float m = S * (1.f / 256.f);
      mu[i][r] = m;
      rs[i][r] = rsqrtf(Q * (1.f / 256.f) - m * m + kEPS);
    }
#pragma unroll
  for (int xc = 0; xc < 4; xc++)
#pragma unroll
    for (int j = 0; j < 2; j++) {
      int col = xc * 64 + wc + j * 16 + fr;
      float g_ = lng[col], b_ = lnb[col];
#pragma unroll
      for (int i = 0; i < 2; i++) {
        int rb = wr + i * 16 + rq;
#pragma unroll
        for (int r = 0; r < 4; r++) {
          float yv = (xacc[xc][i][j][r] - mu[i][r]) * rs[i][r] * g_ + b_;
          A2[(size_t)(bm + rb + r) * 320 + col] = f2bf(yv);
        }
      }
    }
}

// ================= tail: f = A2 @ W2f^T + bbf, + BN stats + last-block finalize =================
__global__ __launch_bounds__(256) void k_tail(const u16* __restrict__ A2,
                                              const u16* __restrict__ W2f,
                                              const float* __restrict__ bbf,
                                              float* __restrict__ fB,
                                              float* __restrict__ pS,
                                              float* __restrict__ pQ,
                                              u32* __restrict__ arrive,
                                              const float* __restrict__ bng,
                                              const float* __restrict__ bnb,
                                              float* __restrict__ coef,
                                              float* __restrict__ shift) {
  __shared__ __align__(16) u16 As[2048];
  __shared__ __align__(16) u16 Bs[2048];
  __shared__ float colS[64][2], colQ[64][2];
  __shared__ u32 lastf;
  const int tid = threadIdx.x;
  const int wave = tid >> 6, lane = tid & 63;
  const int bm = blockIdx.x * 64;
  const int wr = (wave >> 1) * 32, wc = (wave & 1) * 32;
  const int fr = lane & 15, fk = (lane >> 4) * 8, rq = (lane >> 4) * 4;
  const int g = wave * 64 + lane;
  const int grow = g >> 2, gko = (g & 3) * 8;

  f32x4 acc[2][2];
#pragma unroll
  for (int i = 0; i < 2; i++)
#pragma unroll
    for (int j = 0; j < 2; j++)
#pragma unroll
      for (int r = 0; r < 4; r++) acc[i][j][r] = 0.f;
  for (int k0 = 0; k0 < 320; k0 += 32) {
    gll16(A2 + (size_t)(bm + grow) * 320 + k0 + gko, As + g * 8);
    gll16(W2f + (size_t)grow * 320 + k0 + gko, Bs + g * 8);
    __syncthreads();
    short8 af[2], bg[2];
#pragma unroll
    for (int i = 0; i < 2; i++)
      af[i] = *(const short8*)&As[(wr + i * 16 + fr) * 32 + fk];
#pragma unroll
    for (int j = 0; j < 2; j++)
      bg[j] = *(const short8*)&Bs[(wc + j * 16 + fr) * 32 + fk];
#pragma unroll
    for (int i = 0; i < 2; i++)
#pragma unroll
      for (int j = 0; j < 2; j++)
        acc[i][j] = __builtin_amdgcn_mfma_f32_16x16x32_bf16(af[i], bg[j], acc[i][j], 0, 0, 0);
    __syncthreads();
  }
  float cS[2] = {0.f, 0.f}, cQ[2] = {0.f, 0.f};
#pragma unroll
  for (int j = 0; j < 2; j++) {
    int col = wc + j * 16 + fr;
    float bv = bbf[col];
#pragma unroll
    for (int i = 0; i < 2; i++) {
      int rb = wr + i * 16 + rq;
#pragma unroll
      for (int r = 0; r < 4; r++) {
        float v = acc[i][j][r] + bv;
        fB[(size_t)(bm + rb + r) * 64 + col] = v;
        cS[j] += v; cQ[j] += v * v;
      }
    }
  }
#pragma unroll
  for (int off = 16; off < 64; off <<= 1) {
#pragma unroll
    for (int j = 0; j < 2; j++) {
      cS[j] += __shfl_xor(cS[j], off);
      cQ[j] += __shfl_xor(cQ[j], off);
    }
  }
  if ((lane >> 4) == 0) {
#pragma unroll
    for (int j = 0; j < 2; j++) {
      colS[wc + j * 16 + fr][wave >> 1] = cS[j];
      colQ[wc + j * 16 + fr][wave >> 1] = cQ[j];
    }
  }
  __syncthreads();
  if (tid < 64) {
    atomicAdd(&pS[tid], colS[tid][0] + colS[tid][1]);
    atomicAdd(&pQ[tid], colQ[tid][0] + colQ[tid][1]);
  }
  __syncthreads();
  if (tid == 0) {
    __threadfence();
    u32 old = __hip_atomic_fetch_add(arrive, 1u, __ATOMIC_ACQ_REL, __HIP_MEMORY_SCOPE_AGENT);
    lastf = (old == 255) ? 1u : 0u;
  }
  __syncthreads();
  if (lastf && tid < 64) {
    float S = __hip_atomic_load(&pS[tid], __ATOMIC_ACQUIRE, __HIP_MEMORY_SCOPE_AGENT);
    float Q = __hip_atomic_load(&pQ[tid], __ATOMIC_ACQUIRE, __HIP_MEMORY_SCOPE_AGENT);
    float m = S * (1.f / 16384.f);
    float var = Q * (1.f / 16384.f) - m * m;
    float cf = rsqrtf(var + kEPS) * bng[tid];
    coef[tid] = cf;
    shift[tid] = bnb[tid] - m * cf;
  }
}

__global__ __launch_bounds__(256) void k_bnapply(const float* __restrict__ f,
                                                 const float* __restrict__ coef,
                                                 const float* __restrict__ shift,
                                                 float* __restrict__ out) {
  int gid = blockIdx.x * 256 + threadIdx.x;
  int e = gid * 4, col = e & 63;
  float4 v = *(const float4*)(f + e);
  float4 cf = *(const float4*)(coef + col);
  float4 sh = *(const float4*)(shift + col);
  float4 o;
  o.x = fmaxf(v.x * cf.x + sh.x, 0.f);
  o.y = fmaxf(v.y * cf.y + sh.y, 0.f);
  o.z = fmaxf(v.z * cf.z + sh.z, 0.f);
  o.w = fmaxf(v.w * cf.w + sh.w, 0.f);
  *(float4*)(out + e) = o;
}

// ================= launch =================
extern "C" void kernel_launch(void* const* d_in, const int* in_sizes, int n_in,
                              void* d_out, int out_size, void* d_ws, size_t ws_size,
                              hipStream_t stream) {
  (void)in_sizes; (void)n_in; (void)out_size; (void)ws_size;
  const int*   coords = (const int*)d_in[0];
  const float* feats  = (const float*)d_in[1];
  const float* pe_w1  = (const float*)d_in[2];
  const float* pe_b1  = (const float*)d_in[3];
  const float* pe_w2  = (const float*)d_in[4];
  const float* pe_b2  = (const float*)d_in[5];
  const float* proj_w = (const float*)d_in[6];
  const float* proj_b = (const float*)d_in[7];
  const float* wq  = (const float*)d_in[8];
  const float* bq  = (const float*)d_in[9];
  const float* wk  = (const float*)d_in[10];
  const float* bk  = (const float*)d_in[11];
  const float* wv  = (const float*)d_in[12];
  const float* bv  = (const float*)d_in[13];
  const float* wo  = (const float*)d_in[14];
  const float* bo  = (const float*)d_in[15];
  const float* fw1 = (const float*)d_in[16];
  const float* fb1 = (const float*)d_in[17];
  const float* fw2 = (const float*)d_in[18];
  const float* fb2 = (const float*)d_in[19];
  const float* lng = (const float*)d_in[20];
  const float* lnb = (const float*)d_in[21];
  const float* uw1 = (const float*)d_in[22];
  const float* ub1 = (const float*)d_in[23];
  const float* uw2 = (const float*)d_in[24];
  const float* ub2 = (const float*)d_in[25];
  const float* bng = (const float*)d_in[26];
  const float* bnb = (const float*)d_in[27];
  float* out = (float*)d_out;

  char* Wc = (char*)d_ws;
  const size_t MB = 1u << 20;
  u16*   A1    = (u16*)(Wc + 0 * MB);    // 6MB
  u16*   QKVb  = (u16*)(Wc + 6 * MB);    // 24MB
  u16*   aoInB = (u16*)(Wc + 30 * MB);   // 8MB
  u16*   A2    = (u16*)(Wc + 38 * MB);   // 10MB  [y | feats]
  float* fB    = (float*)(Wc + 48 * MB); // 4MB

  u16* qkvT  = (u16*)(Wc + 52 * MB);     // 768 x 256
  u16* woT   = qkvT + 196608;            // 256 x 256
  u16* fw1T  = woT + 65536;              // 512 x 256
  u16* fw2T  = fw1T + 131072;            // 256 x 512
  u16* W1T   = fw2T + 131072;            // 256 x 192
  u16* W2f   = W1T + 49152;              // 64 x 320
  float* pbc = (float*)(W2f + 20480);    // 256
  float* bbf = pbc + 256;                // 64

  u32* Z      = (u32*)(Wc + 56 * MB);
  u32* cnt    = Z;                        // 16384   (zeroed)
  u32* cursor = Z + 16384;                // 16384   (zeroed)
  float* pS   = (float*)(Z + 32768);      // 64      (zeroed)
  float* pQ   = (float*)(Z + 32832);      // 64      (zeroed)
  u32* bar    = Z + 32896;                // (zeroed)
  u32* arrive = Z + 32897;                // (zeroed)
  float* coefb = (float*)(Z + 32912);     // 64
  float* shb   = coefb + 64;              // 64
  u32* startb = Z + 33280;                // 16384
  u32* pts    = Z + 49664;                // 16384 (+slack)
  int* idxb   = (int*)(Z + 82432);        // N*16

  WSet ws;
  ws.s[0] = wq;     ws.d[0] = qkvT;          ws.K[0] = 256; ws.N[0] = 256; ws.dstride[0] = 256; ws.coff[0] = 0;
  ws.s[1] = wk;     ws.d[1] = qkvT + 65536;  ws.K[1] = 256; ws.N[1] = 256; ws.dstride[1] = 256; ws.coff[1] = 0;
  ws.s[2] = wv;     ws.d[2] = qkvT + 131072; ws.K[2] = 256; ws.N[2] = 256; ws.dstride[2] = 256; ws.coff[2] = 0;
  ws.s[3] = wo;     ws.d[3] = woT;           ws.K[3] = 256; ws.N[3] = 256; ws.dstride[3] = 256; ws.coff[3] = 0;
  ws.s[4] = fw1;    ws.d[4] = fw1T;          ws.K[4] = 256; ws.N[4] = 512; ws.dstride[4] = 256; ws.coff[4] = 0;
  ws.s[5] = fw2;    ws.d[5] = fw2T;          ws.K[5] = 512; ws.N[5] = 256; ws.dstride[5] = 512; ws.coff[5] = 0;
  ws.s[6] = proj_w; ws.d[6] = W1T;           ws.K[6] = 64;  ws.N[6] = 256; ws.dstride[6] = 192; ws.coff[6] = 0;
  ws.s[7] = pe_w2;  ws.d[7] = W1T;           ws.K[7] = 128; ws.N[7] = 256; ws.dstride[7] = 192; ws.coff[7] = 64;

  // 1. setup: zero ctl, weight casts, pbc/W2f/bbf, prep(A1, A2 feats half)
  k_setup<<<dim3(512, 11), 256, 0, stream>>>(ws, Z, proj_b, pe_b2, pbc,
                                             uw1, ub1, uw2, ub2, W2f, bbf,
                                             coords, feats, pe_w1, pe_b1, A1, A2);
  // 2. neighbor pipeline (fused, 64 co-resident blocks)
  k_grid<<<64, 256, 0, stream>>>(coords, cnt, cursor, startb, pts, idxb, bar);
  // 3. src + QKV (row-persistent)
  k_src_qkv<<<256, 256, 0, stream>>>(A1, W1T, pbc, qkvT, QKVb);
  // 4. attention
  k_attn<<<512, 256, 0, stream>>>(QKVb, pts, idxb, bq, bk, bv, aoInB);
  // 5. wo + FFN + residual + LN (row-persistent) -> A2 y half
  k_ffn_ln<<<256, 256, 0, stream>>>(aoInB, woT, bo, fw1T, fb1, fw2T, fb2, lng, lnb, A2);
  // 6. tail GEMM + BN stats + finalize
  k_tail<<<256, 256, 0, stream>>>(A2, W2f, bbf, fB, pS, pQ, arrive, bng, bnb, coefb, shb);
  // 7. BN apply + relu
  k_bnapply<<<1024, 256, 0, stream>>>(fB, coefb, shb, out);
}